// Round 2
// baseline (294.851 us; speedup 1.0000x reference)
//
#include <hip/hip_runtime.h>
#include <hip/hip_bf16.h>
#include <hip/hip_cooperative_groups.h>
#include <math.h>

namespace cg = cooperative_groups;

#define HF 96
#define WF 160
#define CH 100
#define HH 48      // HF/2
#define HW 80      // WF/2
#define NPIX 3840  // HH*HW
#define MD 9
#define KD 19
#define K2 361
#define NMAX 8

// ws float offsets. Deliberate overlap-guards: OOB-masked reads off Yt/ys edges
// land in the neighboring arrays (values unused — mask selects 1.0).
#define OFF_XT 0
#define OFF_YT (CH*NPIX)               // 384000
#define OFF_XS (2*CH*NPIX)             // 768000
#define OFF_YS (2*CH*NPIX + NPIX)      // 771840
#define OFF_DH (2*CH*NPIX + 2*NPIX)    // 775680  (bf16, k-major: [K2][NPIX])

#define NBLK 600
#define NTHR 256
#define NWAVE (NBLK * 4)   // 2400 waves

// One cooperative kernel, three phases, two grid syncs.
// __launch_bounds__(256,3): caps VGPR ~168 -> >=3 blocks/CU -> 768 >= 600
// co-resident blocks guaranteed (LDS 19KB/block is not the limiter).
template <int N>
__global__ __launch_bounds__(256, 3) void fused_kernel(
    const float* __restrict__ q, const float* __restrict__ p,
    float* __restrict__ Xt, float* __restrict__ Yt,
    float* __restrict__ xs, float* __restrict__ ys,
    __hip_bfloat16* __restrict__ dh2,
    const int* __restrict__ labels, const int* __restrict__ gt,
    float* __restrict__ out) {
  cg::grid_group grid = cg::this_grid();
  __shared__ float ex[128][21];          // dist c-split exchange (pad 21: conflict-free)
  __shared__ float mm[4][64][N];         // upmin 4-wave min-combine

  // ---------------- Phase A: pool + norms (wave-per-pixel, strided) ----------
  {
    int w = threadIdx.x >> 6, L = threadIdx.x & 63;
    int wg = blockIdx.x * 4 + w;
    for (int pix = wg; pix < NPIX; pix += NWAVE) {
      int i = pix / HW, j = pix - i * HW;
      int base = (2 * i) * WF * CH + (2 * j) * CH;
      float nx = 0.f, ny = 0.f;
      for (int c = L; c < CH; c += 64) {
        int b = base + c;
        float xv = 0.25f * (q[b] + q[b + CH] + q[b + WF * CH] + q[b + WF * CH + CH]);
        float yv = 0.25f * (p[b] + p[b + CH] + p[b + WF * CH] + p[b + WF * CH + CH]);
        Xt[c * NPIX + pix] = xv;
        Yt[c * NPIX + pix] = yv;
        nx = fmaf(xv, xv, nx);
        ny = fmaf(yv, yv, ny);
      }
      for (int s = 32; s > 0; s >>= 1) {
        nx += __shfl_down(nx, s);
        ny += __shfl_down(ny, s);
      }
      if (L == 0) { xs[pix] = nx; ys[pix] = ny; }
    }
  }
  grid.sync();

  // ---------------- Phase B: dist, row-paired + channel-split x2 -------------
  // item = (u, t): t = row-pair*80 + col, u = (dy-pair dp, dx-half h).
  // Threads 0-127 of the block take c in [0,50), threads 128-255 take [50,100)
  // for the SAME 128 items; LDS add combines. 2400 waves -> 2.34/SIMD.
  {
    int half = threadIdx.x >> 7;         // 0: c-low, 1: c-high
    int il = threadIdx.x & 127;
    int item = blockIdx.x * 128 + il;    // 600*128 = 76800 = 1920*40 exactly
    int t = item % 1920, u = item / 1920;  // blocks never straddle u (1920%128==0)
    int dp = u >> 1, h = u & 1;
    int ip = t / HW, j = t - ip * HW;
    int iA = 2 * ip;
    int pixA = iA * HW + j, pixB = pixA + HW;

    bool doA = (dp < KD);                // (row iA,   dy = dp)
    bool doB = (dp >= 1);                // (row iA+1, dy = dp-1)
    int r = iA + dp - MD;                // shared Y row
    bool rowOK = (r >= 0 && r < HH);
    int cbase = j - MD + 10 * h;
    int nd = h ? 9 : 10;
    int kbA = dp * KD + 10 * h;
    int kbB = (dp - 1) * KD + 10 * h;

    float accA[10], accB[10];
#pragma unroll
    for (int d = 0; d < 10; ++d) { accA[d] = 0.f; accB[d] = 0.f; }

    if (rowOK) {
      int c0 = half * 50;
      const float* xpA = Xt + c0 * NPIX + pixA;
      const float* xpB = Xt + c0 * NPIX + pixB;
      const float* yp  = Yt + c0 * NPIX + r * HW + cbase;  // strays <=10 floats
                                                           // OOB into adjacent ws
                                                           // array, value masked.
#pragma unroll 2
      for (int c = 0; c < 50; ++c) {
        float xa = *xpA, xb = *xpB;
#pragma unroll
        for (int d = 0; d < 10; ++d) {
          float yv = yp[d];
          accA[d] = fmaf(xa, yv, accA[d]);
          accB[d] = fmaf(xb, yv, accB[d]);
        }
        xpA += NPIX; xpB += NPIX; yp += NPIX;
      }
    }
    // combine halves (high half wrote zeros if !rowOK — unused anyway)
    if (half == 1) {
#pragma unroll
      for (int d = 0; d < 10; ++d) { ex[il][d] = accA[d]; ex[il][10 + d] = accB[d]; }
    }
    __syncthreads();
    if (half == 0) {
#pragma unroll
      for (int d = 0; d < 10; ++d) { accA[d] += ex[il][d]; accB[d] += ex[il][10 + d]; }
      if (!rowOK) {
        __hip_bfloat16 one = __float2bfloat16(1.0f);
#pragma unroll
        for (int d = 0; d < 10; ++d) {
          if (d >= nd) break;
          if (doA) dh2[(kbA + d) * NPIX + pixA] = one;
          if (doB) dh2[(kbB + d) * NPIX + pixB] = one;
        }
      } else {
        float xssA = xs[pixA];
        float xssB = xs[pixB];
        const float* ysr = ys + r * HW;
#pragma unroll
        for (int d = 0; d < 10; ++d) {
          if (d >= nd) break;
          int jj = cbase + d;
          bool okc = (jj >= 0) && (jj < HW);
          int jcl = jj < 0 ? 0 : (jj > HW - 1 ? HW - 1 : jj);
          float yss = ysr[jcl];
          if (doA) {
            float s = xssA + yss - 2.f * accA[d];
            float e = __expf(-s);
            float rv = okc ? (1.f - e) / (1.f + e) : 1.0f;
            dh2[(kbA + d) * NPIX + pixA] = __float2bfloat16(rv);
          }
          if (doB) {
            float s = xssB + yss - 2.f * accB[d];
            float e = __expf(-s);
            float rv = okc ? (1.f - e) / (1.f + e) : 1.0f;
            dh2[(kbB + d) * NPIX + pixB] = __float2bfloat16(rv);
          }
        }
      }
    }
  }
  grid.sync();

  // ---------------- Phase C: bilinear upsample + masked min ------------------
  // Block b < 240 handles 64-pixel strip b; 4 waves split k 4 ways (~90 iters).
  if (blockIdx.x < (HF * WF / 64)) {
    int w = threadIdx.x >> 6, lane = threadIdx.x & 63;
    int pixel = blockIdx.x * 64 + lane;
    int I = pixel / WF, J = pixel - I * WF;

    const float sy = (float)((HH - 1.0) / (HF - 1.0));
    const float sx = (float)((HW - 1.0) / (WF - 1.0));
    float py = (float)I * sy;
    int y0 = (int)floorf(py); if (y0 > HH - 2) y0 = HH - 2; if (y0 < 0) y0 = 0;
    float fy = py - (float)y0;
    float px = (float)J * sx;
    int x0 = (int)floorf(px); if (x0 > HW - 2) x0 = HW - 2; if (x0 < 0) x0 = 0;
    float fx = px - (float)x0;
    float w00 = (1.f - fy) * (1.f - fx), w01 = (1.f - fy) * fx;
    float w10 = fy * (1.f - fx),         w11 = fy * fx;
    int np00 = y0 * HW + x0;

    int gtl[N];
    float mins[N];
#pragma unroll
    for (int o = 0; o < N; ++o) { gtl[o] = gt[o]; mins[o] = 1.0f; }

    for (int k = w; k < K2; k += 4) {
      int dy = k / KD, dx = k - dy * KD;
      int P = I + dy - MD, Q = J + dx - MD;
      const __hip_bfloat16* dk = dh2 + k * NPIX + np00;
      float v = w00 * __bfloat162float(dk[0]) + w01 * __bfloat162float(dk[1]) +
                w10 * __bfloat162float(dk[HW]) + w11 * __bfloat162float(dk[HW + 1]);
      if (P >= 0 && P < HF && Q >= 0 && Q < WF) {
        int lab = labels[P * WF + Q];
#pragma unroll
        for (int o = 0; o < N; ++o)
          if (lab == gtl[o]) mins[o] = fminf(mins[o], v);
      }
    }

#pragma unroll
    for (int o = 0; o < N; ++o) mm[w][lane][o] = mins[o];
    __syncthreads();
    if (w == 0) {
#pragma unroll
      for (int o = 0; o < N; ++o) {
        float m = fminf(fminf(mm[0][lane][o], mm[1][lane][o]),
                        fminf(mm[2][lane][o], mm[3][lane][o]));
        out[pixel * N + o] = m;
      }
    }
  }
}

extern "C" void kernel_launch(void* const* d_in, const int* in_sizes, int n_in,
                              void* d_out, int out_size, void* d_ws, size_t ws_size,
                              hipStream_t stream) {
  const float* prev  = (const float*)d_in[0];   // prev_frame_embedding -> y
  const float* query = (const float*)d_in[1];   // query_embedding      -> x
  const int* labels  = (const int*)d_in[2];
  const int* gt      = (const int*)d_in[3];
  int n = in_sizes[3];
  if (n > NMAX) n = NMAX;
  float* ws = (float*)d_ws;
  float* Xt = ws + OFF_XT;
  float* Yt = ws + OFF_YT;
  float* xs = ws + OFF_XS;
  float* ys = ws + OFF_YS;
  __hip_bfloat16* dh2 = (__hip_bfloat16*)(ws + OFF_DH);
  float* out = (float*)d_out;

  void* args[10] = {
    (void*)&query, (void*)&prev, (void*)&Xt, (void*)&Yt, (void*)&xs, (void*)&ys,
    (void*)&dh2, (void*)&labels, (void*)&gt, (void*)&out };

#define LAUNCH(NN) hipLaunchCooperativeKernel( \
      reinterpret_cast<void*>(&fused_kernel<NN>), dim3(NBLK), dim3(NTHR), \
      args, 0, stream)
  switch (n) {
    case 1: LAUNCH(1); break;
    case 2: LAUNCH(2); break;
    case 3: LAUNCH(3); break;
    case 4: LAUNCH(4); break;
    case 5: LAUNCH(5); break;
    case 6: LAUNCH(6); break;
    case 7: LAUNCH(7); break;
    default: LAUNCH(8); break;
  }
#undef LAUNCH
}

// Round 3
// 104.663 us; speedup vs baseline: 2.8172x; 2.8172x over previous
//
#include <hip/hip_runtime.h>
#include <hip/hip_bf16.h>
#include <math.h>

#define HF 96
#define WF 160
#define CH 100
#define HH 48      // HF/2
#define HW 80      // WF/2
#define NPIX 3840  // HH*HW
#define MD 9
#define KD 19
#define K2 361
#define NMAX 8

// ws float offsets. Deliberate overlap-guards: OOB-masked reads off Yt/ys edges
// land in the neighboring arrays (values unused — mask selects 1.0).
// Yt window reads stray at most +9 floats (into xs) / -9 floats (into Xt tail).
#define OFF_XT 0
#define OFF_YT (CH*NPIX)               // 384000
#define OFF_XS (2*CH*NPIX)             // 768000
#define OFF_YS (2*CH*NPIX + NPIX)      // 771840
#define OFF_DH (2*CH*NPIX + 2*NPIX)    // 775680  (bf16, k-major: [K2][NPIX])

typedef float f32x2 __attribute__((ext_vector_type(2)));

// ---------------- Kernel A: pool + norms, channel-major, shuffle-reduced ------
__global__ __launch_bounds__(256) void pool_kernel(
    const float* __restrict__ q, const float* __restrict__ p,
    float* __restrict__ Xt, float* __restrict__ Yt,
    float* __restrict__ xs, float* __restrict__ ys) {
  int w = threadIdx.x >> 6, L = threadIdx.x & 63;
  int pix = blockIdx.x * 4 + w;
  int i = pix / HW, j = pix - i * HW;
  int base = (2 * i) * WF * CH + (2 * j) * CH;
  float nx = 0.f, ny = 0.f;
  for (int c = L; c < CH; c += 64) {
    int b = base + c;
    float xv = 0.25f * (q[b] + q[b + CH] + q[b + WF * CH] + q[b + WF * CH + CH]);
    float yv = 0.25f * (p[b] + p[b + CH] + p[b + WF * CH] + p[b + WF * CH + CH]);
    Xt[c * NPIX + pix] = xv;
    Yt[c * NPIX + pix] = yv;
    nx = fmaf(xv, xv, nx);
    ny = fmaf(yv, yv, ny);
  }
  for (int s = 32; s > 0; s >>= 1) {
    nx += __shfl_down(nx, s);
    ny += __shfl_down(ny, s);
  }
  if (L == 0) { xs[pix] = nx; ys[pix] = ny; }
}

// ---------------- Kernel B: dist — 4-row grouping + pk-f32 FMA + c-split x4 ---
// Rows 4q..4q+3 paired with dy = dp..dp-3 all share Y row r = 4q+dp-9:
// 14 loads/c (4 X + 10 shared Y) feed 40 FMAs (20 v_pk_fma_f32).
// item = (quad-row t, u=(dp,h)); 960*44 items; block = 64 items x 4 c-quarters
// (25 channels each), LDS stride-41 conflict-free combine. Grid = 660.
__global__ __launch_bounds__(256, 3) void dist_kernel(
    const float* __restrict__ Xt, const float* __restrict__ Yt,
    const float* __restrict__ xs, const float* __restrict__ ys,
    __hip_bfloat16* __restrict__ dh2) {
  __shared__ float ex[3][64][41];   // stride 41: il*41%32 hits all banks, 2 lanes/bank = free
  int il = threadIdx.x & 63;
  int qtr = threadIdx.x >> 6;
  int item = blockIdx.x * 64 + il;       // 660*64 = 42240 = 960*44
  int t = item % 960, u = item / 960;    // 960%64==0: block never straddles u
  int dp = u >> 1, h = u & 1;            // dp = 0..21
  int ipq = t / HW, j = t - ipq * HW;    // ipq = 0..11 (row quad), j = col
  int pix0 = ipq * (4 * HW) + j;         // pixel of row 4*ipq
  int r = 4 * ipq + dp - MD;             // shared Y row for the quad
  bool rowOK = (r >= 0 && r < HH);
  int cbase = j - MD + 10 * h;
  int nd = h ? 9 : 10;

  f32x2 accA[10], accB[10];              // accA: rows {0,1}, accB: rows {2,3}
#pragma unroll
  for (int d = 0; d < 10; ++d) { accA[d] = (f32x2){0.f, 0.f}; accB[d] = (f32x2){0.f, 0.f}; }

  if (rowOK) {
    const float* xp = Xt + (qtr * 25) * NPIX + pix0;
    const float* yp = Yt + (qtr * 25) * NPIX + r * HW + cbase;  // strays <=9 floats
                                                                // into adjacent ws
                                                                // arrays; masked.
#pragma unroll 5
    for (int c = 0; c < 25; ++c) {
      float x0 = xp[0], x1 = xp[HW], x2 = xp[2 * HW], x3 = xp[3 * HW];
      f32x2 xA = {x0, x1}, xB = {x2, x3};
#pragma unroll
      for (int d = 0; d < 10; ++d) {
        float yv = yp[d];
        f32x2 yy = {yv, yv};
        accA[d] = __builtin_elementwise_fma(xA, yy, accA[d]);
        accB[d] = __builtin_elementwise_fma(xB, yy, accB[d]);
      }
      xp += NPIX; yp += NPIX;
    }
  }

  if (qtr > 0 && rowOK) {
#pragma unroll
    for (int d = 0; d < 10; ++d) {
      ex[qtr - 1][il][4 * d + 0] = accA[d].x;
      ex[qtr - 1][il][4 * d + 1] = accA[d].y;
      ex[qtr - 1][il][4 * d + 2] = accB[d].x;
      ex[qtr - 1][il][4 * d + 3] = accB[d].y;
    }
  }
  __syncthreads();
  if (qtr != 0) return;

  if (!rowOK) {
    __hip_bfloat16 one = __float2bfloat16(1.0f);
#pragma unroll
    for (int rr = 0; rr < 4; ++rr) {
      int dy = dp - rr;
      if (dy < 0 || dy >= KD) continue;
      int kb = dy * KD + 10 * h;
      int pix = pix0 + rr * HW;
#pragma unroll
      for (int d = 0; d < 10; ++d) {
        if (d >= nd) break;
        dh2[(kb + d) * NPIX + pix] = one;
      }
    }
    return;
  }

#pragma unroll
  for (int q = 0; q < 3; ++q)
#pragma unroll
    for (int d = 0; d < 10; ++d) {
      accA[d].x += ex[q][il][4 * d + 0];
      accA[d].y += ex[q][il][4 * d + 1];
      accB[d].x += ex[q][il][4 * d + 2];
      accB[d].y += ex[q][il][4 * d + 3];
    }

  const float* ysr = ys + r * HW;
  float yss[10];
  bool okc[10];
#pragma unroll
  for (int d = 0; d < 10; ++d) {
    int jj = cbase + d;
    okc[d] = (jj >= 0) && (jj < HW);
    int jcl = jj < 0 ? 0 : (jj > HW - 1 ? HW - 1 : jj);
    yss[d] = ysr[jcl];
  }

#pragma unroll
  for (int rr = 0; rr < 4; ++rr) {
    int dy = dp - rr;
    if (dy < 0 || dy >= KD) continue;
    int kb = dy * KD + 10 * h;
    int pix = pix0 + rr * HW;
    float xss = xs[pix];
#pragma unroll
    for (int d = 0; d < 10; ++d) {
      if (d >= nd) break;
      float a = (rr == 0) ? accA[d].x : (rr == 1) ? accA[d].y
              : (rr == 2) ? accB[d].x : accB[d].y;
      float s = xss + yss[d] - 2.f * a;
      float e = __expf(-s);
      float rv = okc[d] ? (1.f - e) / (1.f + e) : 1.0f;
      dh2[(kb + d) * NPIX + pix] = __float2bfloat16(rv);
    }
  }
}

// ---------------- Kernel C: bilinear upsample + masked min (bf16, k-major) ----
template <int N>
__global__ __launch_bounds__(1024) void upmin_kernel(
    const __hip_bfloat16* __restrict__ dh2, const int* __restrict__ labels,
    const int* __restrict__ gt, float* __restrict__ out) {
  int w = threadIdx.x >> 6;        // 0..15: k-slice
  int lane = threadIdx.x & 63;     // pixel within strip
  int pixel = blockIdx.x * 64 + lane;
  int I = pixel / WF, J = pixel - I * WF;

  const float sy = (float)((HH - 1.0) / (HF - 1.0));
  const float sx = (float)((HW - 1.0) / (WF - 1.0));
  float py = (float)I * sy;
  int y0 = (int)floorf(py); if (y0 > HH - 2) y0 = HH - 2; if (y0 < 0) y0 = 0;
  float fy = py - (float)y0;
  float px = (float)J * sx;
  int x0 = (int)floorf(px); if (x0 > HW - 2) x0 = HW - 2; if (x0 < 0) x0 = 0;
  float fx = px - (float)x0;
  float w00 = (1.f - fy) * (1.f - fx), w01 = (1.f - fy) * fx;
  float w10 = fy * (1.f - fx),         w11 = fy * fx;
  int np00 = y0 * HW + x0;

  int gtl[N];
  float mins[N];
#pragma unroll
  for (int o = 0; o < N; ++o) { gtl[o] = gt[o]; mins[o] = 1.0f; }

  for (int k = w; k < K2; k += 16) {
    int dy = k / KD, dx = k - dy * KD;
    int P = I + dy - MD, Q = J + dx - MD;
    const __hip_bfloat16* dk = dh2 + k * NPIX + np00;
    float v = w00 * __bfloat162float(dk[0]) + w01 * __bfloat162float(dk[1]) +
              w10 * __bfloat162float(dk[HW]) + w11 * __bfloat162float(dk[HW + 1]);
    if (P >= 0 && P < HF && Q >= 0 && Q < WF) {
      int lab = labels[P * WF + Q];
#pragma unroll
      for (int o = 0; o < N; ++o)
        if (lab == gtl[o]) mins[o] = fminf(mins[o], v);
    }
  }

  __shared__ float mm[16][64][N];
#pragma unroll
  for (int o = 0; o < N; ++o) mm[w][lane][o] = mins[o];
  __syncthreads();
  if (w < 8) {
#pragma unroll
    for (int o = 0; o < N; ++o)
      mm[w][lane][o] = fminf(mm[w][lane][o], mm[w + 8][lane][o]);
  }
  __syncthreads();
  if (w < 4) {
#pragma unroll
    for (int o = 0; o < N; ++o)
      mm[w][lane][o] = fminf(mm[w][lane][o], mm[w + 4][lane][o]);
  }
  __syncthreads();
  if (w == 0) {
#pragma unroll
    for (int o = 0; o < N; ++o) {
      float m = fminf(fminf(mm[0][lane][o], mm[1][lane][o]),
                      fminf(mm[2][lane][o], mm[3][lane][o]));
      out[pixel * N + o] = m;
    }
  }
}

extern "C" void kernel_launch(void* const* d_in, const int* in_sizes, int n_in,
                              void* d_out, int out_size, void* d_ws, size_t ws_size,
                              hipStream_t stream) {
  const float* prev  = (const float*)d_in[0];   // prev_frame_embedding -> y
  const float* query = (const float*)d_in[1];   // query_embedding      -> x
  const int* labels  = (const int*)d_in[2];
  const int* gt      = (const int*)d_in[3];
  int n = in_sizes[3];
  if (n > NMAX) n = NMAX;
  float* ws = (float*)d_ws;
  float* Xt = ws + OFF_XT;
  float* Yt = ws + OFF_YT;
  float* xs = ws + OFF_XS;
  float* ys = ws + OFF_YS;
  __hip_bfloat16* dh2 = (__hip_bfloat16*)(ws + OFF_DH);
  float* out = (float*)d_out;

  hipLaunchKernelGGL(pool_kernel, dim3(NPIX / 4), dim3(256), 0, stream,
                     query, prev, Xt, Yt, xs, ys);
  hipLaunchKernelGGL(dist_kernel, dim3(660), dim3(256), 0, stream,
                     Xt, Yt, xs, ys, dh2);
  dim3 ug(HF * WF / 64), ub(1024);
  switch (n) {
    case 1: hipLaunchKernelGGL(upmin_kernel<1>, ug, ub, 0, stream, dh2, labels, gt, out); break;
    case 2: hipLaunchKernelGGL(upmin_kernel<2>, ug, ub, 0, stream, dh2, labels, gt, out); break;
    case 3: hipLaunchKernelGGL(upmin_kernel<3>, ug, ub, 0, stream, dh2, labels, gt, out); break;
    case 4: hipLaunchKernelGGL(upmin_kernel<4>, ug, ub, 0, stream, dh2, labels, gt, out); break;
    case 5: hipLaunchKernelGGL(upmin_kernel<5>, ug, ub, 0, stream, dh2, labels, gt, out); break;
    case 6: hipLaunchKernelGGL(upmin_kernel<6>, ug, ub, 0, stream, dh2, labels, gt, out); break;
    case 7: hipLaunchKernelGGL(upmin_kernel<7>, ug, ub, 0, stream, dh2, labels, gt, out); break;
    default: hipLaunchKernelGGL(upmin_kernel<8>, ug, ub, 0, stream, dh2, labels, gt, out); break;
  }
}

// Round 4
// 103.967 us; speedup vs baseline: 2.8360x; 1.0067x over previous
//
#include <hip/hip_runtime.h>
#include <hip/hip_bf16.h>
#include <math.h>

#define HF 96
#define WF 160
#define CH 100
#define HH 48      // HF/2
#define HW 80      // WF/2
#define NPIX 3840  // HH*HW
#define MD 9
#define KD 19
#define K2 361
#define NMAX 8

// ws float offsets. Deliberate overlap-guards: OOB-masked reads off Yt/ys edges
// land in the neighboring arrays (values unused — mask selects 1.0).
// dist Y-staging reads span rows clamped to [0,47], cols [-12, 92), channels
// up to c=101 (prefetch overread): worst-case addresses stay inside
// [OFF_YT-12, OFF_DH+12) — all within ws; stray values never used.
#define OFF_XT 0
#define OFF_YT (CH*NPIX)               // 384000
#define OFF_XS (2*CH*NPIX)             // 768000
#define OFF_YS (2*CH*NPIX + NPIX)      // 771840
#define OFF_DH (2*CH*NPIX + 2*NPIX)    // 775680  (bf16, k-major: [K2][NPIX])

typedef float f32x2 __attribute__((ext_vector_type(2)));
typedef float f32x4 __attribute__((ext_vector_type(4)));

// ---------------- Kernel A: pool + norms, channel-major, shuffle-reduced ------
__global__ __launch_bounds__(256) void pool_kernel(
    const float* __restrict__ q, const float* __restrict__ p,
    float* __restrict__ Xt, float* __restrict__ Yt,
    float* __restrict__ xs, float* __restrict__ ys) {
  int w = threadIdx.x >> 6, L = threadIdx.x & 63;
  int pix = blockIdx.x * 4 + w;
  int i = pix / HW, j = pix - i * HW;
  int base = (2 * i) * WF * CH + (2 * j) * CH;
  float nx = 0.f, ny = 0.f;
  for (int c = L; c < CH; c += 64) {
    int b = base + c;
    float xv = 0.25f * (q[b] + q[b + CH] + q[b + WF * CH] + q[b + WF * CH + CH]);
    float yv = 0.25f * (p[b] + p[b + CH] + p[b + WF * CH] + p[b + WF * CH + CH]);
    Xt[c * NPIX + pix] = xv;
    Yt[c * NPIX + pix] = yv;
    nx = fmaf(xv, xv, nx);
    ny = fmaf(yv, yv, ny);
  }
  for (int s = 32; s > 0; s >>= 1) {
    nx += __shfl_down(nx, s);
    ny += __shfl_down(ny, s);
  }
  if (L == 0) { xs[pix] = nx; ys[pix] = ny; }
}

// ---------------- Kernel B: dist — 4-row group + LDS-staged Y + c-split x4 ----
// Y windows were 2560B/c/wave through the 64B/cy L1 return path (the bound).
// Now: wave-private double-buffered LDS strip holds the 2 needed Y rows
// (104 floats each, float4-chunk staged by lanes 0..51, reg-prefetched 1 c
// ahead). Y window reads move to the 128B/cy LDS pipe; L1 carries only X
// (1KB/c/wave) + stage (0.78KB). No barriers: wave-coherent LDS.
__global__ __launch_bounds__(256, 3) void dist_kernel(
    const float* __restrict__ Xt, const float* __restrict__ Yt,
    const float* __restrict__ xs, const float* __restrict__ ys,
    __hip_bfloat16* __restrict__ dh2) {
  __shared__ float ex[3][64][41];  // c-split combine; stride 41 -> conflict-free
  __shared__ __align__(16) float ybuf[4][2][212];  // [wave][dbuf][2 groups x 104]
  int il = threadIdx.x & 63;
  int qtr = threadIdx.x >> 6;
  int item = blockIdx.x * 64 + il;       // 660*64 = 42240 = 960*44
  int t = item % 960, u = item / 960;    // 960%64==0: wave never straddles u
  int dp = u >> 1, h = u & 1;            // dp = 0..21
  int ipq = t / HW, j = t - ipq * HW;    // row quad, col
  int pix0 = ipq * (4 * HW) + j;
  int r = 4 * ipq + dp - MD;             // this lane's shared Y row
  bool rowOK = (r >= 0 && r < HH);
  int cbase = j - MD + 10 * h;
  int nd = h ? 9 : 10;

  // wave-uniform: the (up to) 2 row-quads this wave straddles
  int tbase = (blockIdx.x * 64) % 960;
  int ip0 = tbase / HW;
  int g = ipq - ip0;                     // lane's group: 0 or 1
  int r0 = 4 * ip0 + dp - MD;
  int rc0 = r0 < 0 ? 0 : (r0 > HH - 1 ? HH - 1 : r0);
  int r1 = r0 + 4;
  int rc1 = r1 < 0 ? 0 : (r1 > HH - 1 ? HH - 1 : r1);  // clamped: garbage-masked

  f32x2 accA[10], accB[10];              // accA rows {0,1}, accB rows {2,3}
#pragma unroll
  for (int d = 0; d < 10; ++d) { accA[d] = (f32x2){0.f, 0.f}; accB[d] = (f32x2){0.f, 0.f}; }

  if (__any(rowOK)) {
    int sg = il / 26, chunk = il - sg * 26;   // stage slot (lanes 0..51)
    const float* sp = Yt + (qtr * 25) * NPIX + (sg ? rc1 : rc0) * HW + (4 * chunk - 12);
    const float* xp = Xt + (qtr * 25) * NPIX + pix0;
    int lbase = g * 104 + j + 10 * h + 3;     // LDS read base (col -12 <-> idx 0)
    f32x4 sreg;
    if (il < 52) {
      sreg = *(const f32x4*)sp;               // c0
      *(f32x4*)&ybuf[qtr][0][sg * 104 + 4 * chunk] = sreg;
      sp += NPIX;
      sreg = *(const f32x4*)sp;               // c0+1
    }
#pragma unroll 5
    for (int c = 0; c < 25; ++c) {
      float x0 = xp[0], x1 = xp[HW], x2 = xp[2 * HW], x3 = xp[3 * HW];
      xp += NPIX;
      f32x2 xA = {x0, x1}, xB = {x2, x3};
      const float* yb = &ybuf[qtr][c & 1][0];
#pragma unroll
      for (int d = 0; d < 10; ++d) {
        float yv = yb[lbase + d];
        f32x2 yy = {yv, yv};
        accA[d] = __builtin_elementwise_fma(xA, yy, accA[d]);
        accB[d] = __builtin_elementwise_fma(xB, yy, accB[d]);
      }
      if (il < 52) {
        *(f32x4*)&ybuf[qtr][(c + 1) & 1][sg * 104 + 4 * chunk] = sreg;  // c+1
        sp += NPIX;
        sreg = *(const f32x4*)sp;   // c+2; tail overreads stay in ws (doc'd)
      }
    }
  }

  if (qtr > 0 && rowOK) {
#pragma unroll
    for (int d = 0; d < 10; ++d) {
      ex[qtr - 1][il][4 * d + 0] = accA[d].x;
      ex[qtr - 1][il][4 * d + 1] = accA[d].y;
      ex[qtr - 1][il][4 * d + 2] = accB[d].x;
      ex[qtr - 1][il][4 * d + 3] = accB[d].y;
    }
  }
  __syncthreads();
  if (qtr != 0) return;

  if (!rowOK) {
    __hip_bfloat16 one = __float2bfloat16(1.0f);
#pragma unroll
    for (int rr = 0; rr < 4; ++rr) {
      int dy = dp - rr;
      if (dy < 0 || dy >= KD) continue;
      int kb = dy * KD + 10 * h;
      int pix = pix0 + rr * HW;
#pragma unroll
      for (int d = 0; d < 10; ++d) {
        if (d >= nd) break;
        dh2[(kb + d) * NPIX + pix] = one;
      }
    }
    return;
  }

#pragma unroll
  for (int q = 0; q < 3; ++q)
#pragma unroll
    for (int d = 0; d < 10; ++d) {
      accA[d].x += ex[q][il][4 * d + 0];
      accA[d].y += ex[q][il][4 * d + 1];
      accB[d].x += ex[q][il][4 * d + 2];
      accB[d].y += ex[q][il][4 * d + 3];
    }

  const float* ysr = ys + r * HW;
  float yss[10];
  bool okc[10];
#pragma unroll
  for (int d = 0; d < 10; ++d) {
    int jj = cbase + d;
    okc[d] = (jj >= 0) && (jj < HW);
    int jcl = jj < 0 ? 0 : (jj > HW - 1 ? HW - 1 : jj);
    yss[d] = ysr[jcl];
  }

#pragma unroll
  for (int rr = 0; rr < 4; ++rr) {
    int dy = dp - rr;
    if (dy < 0 || dy >= KD) continue;
    int kb = dy * KD + 10 * h;
    int pix = pix0 + rr * HW;
    float xss = xs[pix];
#pragma unroll
    for (int d = 0; d < 10; ++d) {
      if (d >= nd) break;
      float a = (rr == 0) ? accA[d].x : (rr == 1) ? accA[d].y
              : (rr == 2) ? accB[d].x : accB[d].y;
      float s = xss + yss[d] - 2.f * a;
      float e = __expf(-s);
      float rv = okc[d] ? (1.f - e) / (1.f + e) : 1.0f;
      dh2[(kb + d) * NPIX + pix] = __float2bfloat16(rv);
    }
  }
}

// ---------------- Kernel C: bilinear upsample + masked min (bf16, k-major) ----
// Tap pairs loaded as single dwords (bit-exact bf16 unpack) -> 2 loads/k.
template <int N>
__global__ __launch_bounds__(1024) void upmin_kernel(
    const __hip_bfloat16* __restrict__ dh2, const int* __restrict__ labels,
    const int* __restrict__ gt, float* __restrict__ out) {
  int w = threadIdx.x >> 6;        // 0..15: k-slice
  int lane = threadIdx.x & 63;     // pixel within strip
  int pixel = blockIdx.x * 64 + lane;
  int I = pixel / WF, J = pixel - I * WF;

  const float sy = (float)((HH - 1.0) / (HF - 1.0));
  const float sx = (float)((HW - 1.0) / (WF - 1.0));
  float py = (float)I * sy;
  int y0 = (int)floorf(py); if (y0 > HH - 2) y0 = HH - 2; if (y0 < 0) y0 = 0;
  float fy = py - (float)y0;
  float px = (float)J * sx;
  int x0 = (int)floorf(px); if (x0 > HW - 2) x0 = HW - 2; if (x0 < 0) x0 = 0;
  float fx = px - (float)x0;
  float w00 = (1.f - fy) * (1.f - fx), w01 = (1.f - fy) * fx;
  float w10 = fy * (1.f - fx),         w11 = fy * fx;
  int np00 = y0 * HW + x0;

  int gtl[N];
  float mins[N];
#pragma unroll
  for (int o = 0; o < N; ++o) { gtl[o] = gt[o]; mins[o] = 1.0f; }

  for (int k = w; k < K2; k += 16) {
    int dy = k / KD, dx = k - dy * KD;
    int P = I + dy - MD, Q = J + dx - MD;
    const __hip_bfloat16* dk = dh2 + k * NPIX + np00;
    unsigned int u01, u23;
    __builtin_memcpy(&u01, dk, 4);        // dk[0], dk[1]
    __builtin_memcpy(&u23, dk + HW, 4);   // dk[HW], dk[HW+1]
    float f00 = __uint_as_float(u01 << 16);
    float f01 = __uint_as_float(u01 & 0xffff0000u);
    float f10 = __uint_as_float(u23 << 16);
    float f11 = __uint_as_float(u23 & 0xffff0000u);
    float v = w00 * f00 + w01 * f01 + w10 * f10 + w11 * f11;
    if (P >= 0 && P < HF && Q >= 0 && Q < WF) {
      int lab = labels[P * WF + Q];
#pragma unroll
      for (int o = 0; o < N; ++o)
        if (lab == gtl[o]) mins[o] = fminf(mins[o], v);
    }
  }

  __shared__ float mm[16][64][N];
#pragma unroll
  for (int o = 0; o < N; ++o) mm[w][lane][o] = mins[o];
  __syncthreads();
  if (w < 8) {
#pragma unroll
    for (int o = 0; o < N; ++o)
      mm[w][lane][o] = fminf(mm[w][lane][o], mm[w + 8][lane][o]);
  }
  __syncthreads();
  if (w < 4) {
#pragma unroll
    for (int o = 0; o < N; ++o)
      mm[w][lane][o] = fminf(mm[w][lane][o], mm[w + 4][lane][o]);
  }
  __syncthreads();
  if (w == 0) {
#pragma unroll
    for (int o = 0; o < N; ++o) {
      float m = fminf(fminf(mm[0][lane][o], mm[1][lane][o]),
                      fminf(mm[2][lane][o], mm[3][lane][o]));
      out[pixel * N + o] = m;
    }
  }
}

extern "C" void kernel_launch(void* const* d_in, const int* in_sizes, int n_in,
                              void* d_out, int out_size, void* d_ws, size_t ws_size,
                              hipStream_t stream) {
  const float* prev  = (const float*)d_in[0];   // prev_frame_embedding -> y
  const float* query = (const float*)d_in[1];   // query_embedding      -> x
  const int* labels  = (const int*)d_in[2];
  const int* gt      = (const int*)d_in[3];
  int n = in_sizes[3];
  if (n > NMAX) n = NMAX;
  float* ws = (float*)d_ws;
  float* Xt = ws + OFF_XT;
  float* Yt = ws + OFF_YT;
  float* xs = ws + OFF_XS;
  float* ys = ws + OFF_YS;
  __hip_bfloat16* dh2 = (__hip_bfloat16*)(ws + OFF_DH);
  float* out = (float*)d_out;

  hipLaunchKernelGGL(pool_kernel, dim3(NPIX / 4), dim3(256), 0, stream,
                     query, prev, Xt, Yt, xs, ys);
  hipLaunchKernelGGL(dist_kernel, dim3(660), dim3(256), 0, stream,
                     Xt, Yt, xs, ys, dh2);
  dim3 ug(HF * WF / 64), ub(1024);
  switch (n) {
    case 1: hipLaunchKernelGGL(upmin_kernel<1>, ug, ub, 0, stream, dh2, labels, gt, out); break;
    case 2: hipLaunchKernelGGL(upmin_kernel<2>, ug, ub, 0, stream, dh2, labels, gt, out); break;
    case 3: hipLaunchKernelGGL(upmin_kernel<3>, ug, ub, 0, stream, dh2, labels, gt, out); break;
    case 4: hipLaunchKernelGGL(upmin_kernel<4>, ug, ub, 0, stream, dh2, labels, gt, out); break;
    case 5: hipLaunchKernelGGL(upmin_kernel<5>, ug, ub, 0, stream, dh2, labels, gt, out); break;
    case 6: hipLaunchKernelGGL(upmin_kernel<6>, ug, ub, 0, stream, dh2, labels, gt, out); break;
    case 7: hipLaunchKernelGGL(upmin_kernel<7>, ug, ub, 0, stream, dh2, labels, gt, out); break;
    default: hipLaunchKernelGGL(upmin_kernel<8>, ug, ub, 0, stream, dh2, labels, gt, out); break;
  }
}